// Round 3
// baseline (231.028 us; speedup 1.0000x reference)
//
#include <hip/hip_runtime.h>
#include <hip/hip_bf16.h>
#include <stdint.h>
#include <stddef.h>

// GlobalLSTMCell — inputs f32 (per reference + R1/R2 evidence), output f32
// (R2 evidence: c-values aliased into f32-decoded h region at exactly max|c|).
//   ifo = sigmoid(x@W_ifo_x + b_ifo_x + h@W_ifo_h + b_ifo_h); i,f,o = split
//   a   = tanh(x@W_b_x + b_b_x + h@W_b_h + b_b_h)
//   c   = i*a + f*c_prev ; h = o*tanh(c) ; out = [h ; c] as f32.
// Compute: bf16 MFMA (threshold 9.56e-2 permits). Pipeline:
//   xh_pack: [x|h] -> Xcat bf16 [4096][2048] (ws)
//   wt_pack: weights -> Wt bf16 [4096][2048], n' gate-interleaved, k-contiguous (ws)
//   lstm_fused: 128x128 MFMA GEMM, global_load_lds(16B) staging, fused epilogue.

#define BATCH 4096
#define FEAT  1024
#define HID   1024
#define NCAT  4096
#define KCAT  2048

typedef __attribute__((ext_vector_type(8))) __bf16 bf16x8;
typedef __attribute__((ext_vector_type(4))) float  floatx4;

__device__ __forceinline__ unsigned short f2bf(float f) {
    __hip_bfloat16 b = __float2bfloat16(f);
    return *reinterpret_cast<unsigned short*>(&b);
}
__device__ __forceinline__ void gl2lds16(const unsigned short* g, unsigned short* l) {
    __builtin_amdgcn_global_load_lds(
        (const __attribute__((address_space(1))) void*)g,
        (__attribute__((address_space(3))) void*)l, 16, 0, 0);
}

// ---------------- input pack: Xcat[m][k] = bf16([x | h_prev]) ----------------
__global__ __launch_bounds__(256)
void xh_pack(const float* __restrict__ x, const float* __restrict__ h,
             unsigned short* __restrict__ Xcat) {
    const int t = threadIdx.x;
    const int m = blockIdx.x;
    const float* src = (t < 128) ? (x + (size_t)m * FEAT + t * 8)
                                 : (h + (size_t)m * HID + (t - 128) * 8);
    float4 v0 = *(const float4*)src;
    float4 v1 = *(const float4*)(src + 4);
    union { unsigned short s16[8]; uint4 v; } pk;
    pk.s16[0] = f2bf(v0.x); pk.s16[1] = f2bf(v0.y);
    pk.s16[2] = f2bf(v0.z); pk.s16[3] = f2bf(v0.w);
    pk.s16[4] = f2bf(v1.x); pk.s16[5] = f2bf(v1.y);
    pk.s16[6] = f2bf(v1.z); pk.s16[7] = f2bf(v1.w);
    *(uint4*)(Xcat + (size_t)m * KCAT + t * 8) = pk.v;
}

// ---------------- weight pack/transpose ----------------
// Virtual W_cat[k][q], k in [0,2048) (k<1024: x-weights, else h-weights),
// q in [0,4096): q<3072 -> W_ifo[:,q] (g=q>>10, j=q&1023); else W_b[:,q-3072] (g=3).
// Dest: Wt[np][k] bf16, np = (j>>4)*64 + g*16 + (j&15).
#define TP_PAD 65
__global__ __launch_bounds__(256)
void wt_pack(const float* __restrict__ Wix, const float* __restrict__ Wih,
             const float* __restrict__ Wbx, const float* __restrict__ Wbh,
             unsigned short* __restrict__ Wt) {
    __shared__ unsigned short tile[64 * TP_PAD];
    const int t  = threadIdx.x;
    const int k0 = blockIdx.x * 64;
    const int q0 = blockIdx.y * 64;
    const float* src; int stride, cb;
    if (q0 < 3072) { src = (k0 < FEAT) ? Wix : Wih; stride = 3072; cb = q0; }
    else           { src = (k0 < FEAT) ? Wbx : Wbh; stride = 1024; cb = q0 - 3072; }
    const int krow = (k0 < FEAT) ? k0 : (k0 - FEAT);
    {   // load 64x64 (k x q) coalesced on q, convert to bf16
        int kl = t >> 2;
        int c0 = (t & 3) * 16;
        const float* s = src + (size_t)(krow + kl) * stride + cb + c0;
        unsigned short tmp[16];
#pragma unroll
        for (int u = 0; u < 16; u += 4) {
            float4 v = *(const float4*)(s + u);
            tmp[u + 0] = f2bf(v.x); tmp[u + 1] = f2bf(v.y);
            tmp[u + 2] = f2bf(v.z); tmp[u + 3] = f2bf(v.w);
        }
#pragma unroll
        for (int u = 0; u < 16; ++u) tile[kl * TP_PAD + c0 + u] = tmp[u];
    }
    __syncthreads();
    {   // transpose out: thread = (q-col nl, k-chunk seg)
        int nl = t >> 2, seg = t & 3;
        int q = q0 + nl;
        int g, j;
        if (q < 3072) { g = q >> 10; j = q & 1023; }
        else          { g = 3;       j = q - 3072; }
        int np = ((j >> 4) << 6) + (g << 4) + (j & 15);
        union { unsigned short s16[16]; uint4 v[2]; } pk;
#pragma unroll
        for (int u = 0; u < 16; ++u)
            pk.s16[u] = tile[(seg * 16 + u) * TP_PAD + nl];
        uint4* dst = (uint4*)(Wt + (size_t)np * KCAT + k0 + seg * 16);
        dst[0] = pk.v[0];
        dst[1] = pk.v[1];
    }
}

// ---------------- fused GEMM + LSTM epilogue ----------------
#define BM 128
#define BN 128
#define BK 32

__global__ __launch_bounds__(256)
void lstm_fused(const unsigned short* __restrict__ Xcat,
                const unsigned short* __restrict__ Wt,
                const float* __restrict__ c_prev,
                const float* __restrict__ bix, const float* __restrict__ bih,
                const float* __restrict__ bbx, const float* __restrict__ bbh,
                float* __restrict__ out_h, float* __restrict__ out_c) {
    __shared__ unsigned short As[BM * BK];   // 8 KB
    __shared__ unsigned short Bs[BN * BK];   // 8 KB
    const int t    = threadIdx.x;
    const int lane = t & 63;
    const int wave = t >> 6;
    const int wm   = (wave >> 1) * 64;
    const int wn   = (wave & 1) * 64;
    const int m0   = blockIdx.y * BM;
    const int n0   = blockIdx.x * BN;

    floatx4 acc[4][4];
#pragma unroll
    for (int i = 0; i < 4; ++i)
#pragma unroll
        for (int g = 0; g < 4; ++g) acc[i][g] = (floatx4){0.f, 0.f, 0.f, 0.f};

    const int lrow = t >> 2;        // 0..63
    const int lcol = (t & 3) * 8;   // k offset within BK

    for (int kk = 0; kk < KCAT; kk += BK) {
        __syncthreads();   // previous tile fully consumed
        gl2lds16(Xcat + (size_t)(m0 + lrow)      * KCAT + kk + lcol, &As[t * 8]);
        gl2lds16(Xcat + (size_t)(m0 + lrow + 64) * KCAT + kk + lcol, &As[t * 8 + 2048]);
        gl2lds16(Wt   + (size_t)(n0 + lrow)      * KCAT + kk + lcol, &Bs[t * 8]);
        gl2lds16(Wt   + (size_t)(n0 + lrow + 64) * KCAT + kk + lcol, &Bs[t * 8 + 2048]);
        __syncthreads();   // drains vmcnt(0) for global_load_lds

        const int lm = lane & 15;
        const int lk = (lane >> 4) * 8;
        bf16x8 a[4], b[4];
#pragma unroll
        for (int i = 0; i < 4; ++i)
            a[i] = *(const bf16x8*)&As[(wm + i * 16 + lm) * BK + lk];
#pragma unroll
        for (int g = 0; g < 4; ++g)
            b[g] = *(const bf16x8*)&Bs[(wn + g * 16 + lm) * BK + lk];
#pragma unroll
        for (int i = 0; i < 4; ++i)
#pragma unroll
            for (int g = 0; g < 4; ++g)
                acc[i][g] = __builtin_amdgcn_mfma_f32_16x16x32_bf16(a[i], b[g], acc[i][g], 0, 0, 0);
    }

    // Epilogue: acc[i][g][r] = preact of gate g (i,f,o,a) at
    // m = m0+wm+i*16+(lane>>4)*4+r, j = ((n0+wn)>>6)*16 + (lane&15).
    const int lm = lane & 15;
    const int j  = (((n0 + wn) >> 6) << 4) + lm;
    const float bi = bix[j]           + bih[j];
    const float bf = bix[HID + j]     + bih[HID + j];
    const float bo = bix[2 * HID + j] + bih[2 * HID + j];
    const float ba = bbx[j]           + bbh[j];
#pragma unroll
    for (int i = 0; i < 4; ++i) {
#pragma unroll
        for (int r = 0; r < 4; ++r) {
            int m = m0 + wm + i * 16 + ((lane >> 4) * 4) + r;
            float pi = acc[i][0][r] + bi;
            float pf = acc[i][1][r] + bf;
            float po = acc[i][2][r] + bo;
            float pa = acc[i][3][r] + ba;
            float ig = 1.f / (1.f + __expf(-pi));
            float fg = 1.f / (1.f + __expf(-pf));
            float og = 1.f / (1.f + __expf(-po));
            float av = 2.f / (1.f + __expf(-2.f * pa)) - 1.f;
            float cp = c_prev[(size_t)m * HID + j];
            float cv = ig * av + fg * cp;
            float hv = og * (2.f / (1.f + __expf(-2.f * cv)) - 1.f);
            out_h[(size_t)m * HID + j] = hv;
            out_c[(size_t)m * HID + j] = cv;
        }
    }
}

// ---------------- naive fallback (ws too small) ----------------
__global__ void naive_lstm(const float* __restrict__ x, const float* __restrict__ h,
                           const float* __restrict__ cvp,
                           const float* __restrict__ Wix, const float* __restrict__ bix,
                           const float* __restrict__ Wih, const float* __restrict__ bih,
                           const float* __restrict__ Wbx, const float* __restrict__ bbx,
                           const float* __restrict__ Wbh, const float* __restrict__ bbh,
                           float* __restrict__ out_h, float* __restrict__ out_c) {
    const int j = blockIdx.x * 256 + threadIdx.x;
    const int m = blockIdx.y;
    float ai = 0.f, af = 0.f, ao = 0.f, aa = 0.f;
    for (int k = 0; k < FEAT; ++k) {
        float xk = x[(size_t)m * FEAT + k];
        ai += xk * Wix[(size_t)k * 3072 + j];
        af += xk * Wix[(size_t)k * 3072 + HID + j];
        ao += xk * Wix[(size_t)k * 3072 + 2 * HID + j];
        aa += xk * Wbx[(size_t)k * HID + j];
    }
    for (int k = 0; k < HID; ++k) {
        float hk = h[(size_t)m * HID + k];
        ai += hk * Wih[(size_t)k * 3072 + j];
        af += hk * Wih[(size_t)k * 3072 + HID + j];
        ao += hk * Wih[(size_t)k * 3072 + 2 * HID + j];
        aa += hk * Wbh[(size_t)k * HID + j];
    }
    ai += bix[j] + bih[j];
    af += bix[HID + j] + bih[HID + j];
    ao += bix[2 * HID + j] + bih[2 * HID + j];
    aa += bbx[j] + bbh[j];
    float ig = 1.f / (1.f + __expf(-ai));
    float fg = 1.f / (1.f + __expf(-af));
    float og = 1.f / (1.f + __expf(-ao));
    float av = 2.f / (1.f + __expf(-2.f * aa)) - 1.f;
    float cp = cvp[(size_t)m * HID + j];
    float cc = ig * av + fg * cp;
    float hh = og * (2.f / (1.f + __expf(-2.f * cc)) - 1.f);
    out_h[(size_t)m * HID + j] = hh;
    out_c[(size_t)m * HID + j] = cc;
}

extern "C" void kernel_launch(void* const* d_in, const int* in_sizes, int n_in,
                              void* d_out, int out_size, void* d_ws, size_t ws_size,
                              hipStream_t stream) {
    const float* x   = (const float*)d_in[0];
    const float* h   = (const float*)d_in[1];
    const float* c   = (const float*)d_in[2];
    const float* Wix = (const float*)d_in[3];
    const float* bix = (const float*)d_in[4];
    const float* Wih = (const float*)d_in[5];
    const float* bih = (const float*)d_in[6];
    const float* Wbx = (const float*)d_in[7];
    const float* bbx = (const float*)d_in[8];
    const float* Wbh = (const float*)d_in[9];
    const float* bbh = (const float*)d_in[10];

    float* out_h = (float*)d_out;
    float* out_c = out_h + (size_t)BATCH * HID;

    const size_t WT_BYTES = (size_t)NCAT * KCAT * 2;    // 16 MiB
    const size_t XC_BYTES = (size_t)BATCH * KCAT * 2;   // 16 MiB
    if (ws_size >= WT_BYTES + XC_BYTES) {
        unsigned short* Wt   = (unsigned short*)d_ws;
        unsigned short* Xcat = (unsigned short*)((char*)d_ws + WT_BYTES);
        xh_pack<<<BATCH, 256, 0, stream>>>(x, h, Xcat);
        wt_pack<<<dim3(KCAT / 64, NCAT / 64), 256, 0, stream>>>(Wix, Wih, Wbx, Wbh, Wt);
        lstm_fused<<<dim3(NCAT / BN, BATCH / BM), 256, 0, stream>>>(
            Xcat, Wt, c, bix, bih, bbx, bbh, out_h, out_c);
    } else {
        naive_lstm<<<dim3(HID / 256, BATCH), 256, 0, stream>>>(
            x, h, c, Wix, bix, Wih, bih, Wbx, bbx, Wbh, bbh, out_h, out_c);
    }
}

// Round 4
// 228.847 us; speedup vs baseline: 1.0095x; 1.0095x over previous
//
#include <hip/hip_runtime.h>
#include <hip/hip_bf16.h>
#include <stdint.h>
#include <stddef.h>

// GlobalLSTMCell — f32 in/out, bf16 MFMA compute.
//   ifo = sigmoid(x@W_ifo_x + b_ifo_x + h@W_ifo_h + b_ifo_h); i,f,o = split
//   a   = tanh(x@W_b_x + b_b_x + h@W_b_h + b_b_h)
//   c   = i*a + f*c_prev ; h = o*tanh(c) ; out = [h ; c] f32.
// R3: 231 us total, GEMM 110.9 us (620 TF), packs ~120 us -> this round:
//  - pack_all: xh_pack + wt_pack fused into ONE kernel (one launch, vectorized
//    LDS writes, 72-u16 padded transpose tile).
//  - lstm_fused: XOR-swizzled LDS chunk placement (cs = c ^ ((r+(r>>2))&3)) to
//    cut 8-way ds_read_b128 bank conflicts to 2-way while preserving the
//    global_load_lds contiguous-dest constraint (permute global chunk per lane).

#define BATCH 4096
#define FEAT  1024
#define HID   1024
#define NCAT  4096
#define KCAT  2048

typedef __attribute__((ext_vector_type(8))) __bf16 bf16x8;
typedef __attribute__((ext_vector_type(4))) float  floatx4;

__device__ __forceinline__ unsigned short f2bf(float f) {
    __hip_bfloat16 b = __float2bfloat16(f);
    return *reinterpret_cast<unsigned short*>(&b);
}
__device__ __forceinline__ void gl2lds16(const unsigned short* g, unsigned short* l) {
    __builtin_amdgcn_global_load_lds(
        (const __attribute__((address_space(1))) void*)g,
        (__attribute__((address_space(3))) void*)l, 16, 0, 0);
}

// ---------------- fused pack: Xcat + Wt ----------------
// blocks [0,4096):  Xcat[m][k] = bf16([x | h_prev][m][k])
// blocks [4096,6144): weight transpose tile.
//   Virtual W_cat[k][q]: k<1024 x-weights else h-weights; q<3072 -> W_ifo (g=q>>10,
//   j=q&1023) else W_b (g=3, j=q-3072). Dest Wt[np][k], np=(j>>4)*64+g*16+(j&15).
#define TP_PAD 72   // u16 row stride; 144 B = 9*16 -> uint4-aligned rows, odd word shift
__global__ __launch_bounds__(256)
void pack_all(const float* __restrict__ x, const float* __restrict__ h,
              const float* __restrict__ Wix, const float* __restrict__ Wih,
              const float* __restrict__ Wbx, const float* __restrict__ Wbh,
              unsigned short* __restrict__ Xcat, unsigned short* __restrict__ Wt) {
    __shared__ unsigned short tile[64 * TP_PAD];
    const int t = threadIdx.x;
    const int b = blockIdx.x;
    if (b < BATCH) {
        // ---- xh part: one row m, 2048 elems, 8 per thread ----
        const int m = b;
        const float* src = (t < 128) ? (x + (size_t)m * FEAT + t * 8)
                                     : (h + (size_t)m * HID + (t - 128) * 8);
        float4 v0 = *(const float4*)src;
        float4 v1 = *(const float4*)(src + 4);
        union { unsigned short s16[8]; uint4 v; } pk;
        pk.s16[0] = f2bf(v0.x); pk.s16[1] = f2bf(v0.y);
        pk.s16[2] = f2bf(v0.z); pk.s16[3] = f2bf(v0.w);
        pk.s16[4] = f2bf(v1.x); pk.s16[5] = f2bf(v1.y);
        pk.s16[6] = f2bf(v1.z); pk.s16[7] = f2bf(v1.w);
        *(uint4*)(Xcat + (size_t)m * KCAT + t * 8) = pk.v;
        return;
    }
    // ---- wt part: 64x64 tile transpose ----
    const int tid = b - BATCH;
    const int k0  = (tid & 31) * 64;
    const int q0  = (tid >> 5) * 64;
    const float* src; int stride, cb;
    if (q0 < 3072) { src = (k0 < FEAT) ? Wix : Wih; stride = 3072; cb = q0; }
    else           { src = (k0 < FEAT) ? Wbx : Wbh; stride = 1024; cb = q0 - 3072; }
    const int krow = (k0 < FEAT) ? k0 : (k0 - FEAT);
    {   // load 64x64 (k x q) coalesced on q, cvt bf16, vector LDS stores
        int kl = t >> 2;
        int c0 = (t & 3) * 16;
        const float* s = src + (size_t)(krow + kl) * stride + cb + c0;
        union { unsigned short s16[16]; uint4 v[2]; } tmp;
#pragma unroll
        for (int u = 0; u < 16; u += 4) {
            float4 v = *(const float4*)(s + u);
            tmp.s16[u + 0] = f2bf(v.x); tmp.s16[u + 1] = f2bf(v.y);
            tmp.s16[u + 2] = f2bf(v.z); tmp.s16[u + 3] = f2bf(v.w);
        }
        *(uint4*)&tile[kl * TP_PAD + c0]     = tmp.v[0];
        *(uint4*)&tile[kl * TP_PAD + c0 + 8] = tmp.v[1];
    }
    __syncthreads();
    {   // transpose out: thread = (q-col nl, k-chunk seg)
        int nl = t >> 2, seg = t & 3;
        int q = q0 + nl;
        int g, j;
        if (q < 3072) { g = q >> 10; j = q & 1023; }
        else          { g = 3;       j = q - 3072; }
        int np = ((j >> 4) << 6) + (g << 4) + (j & 15);
        union { unsigned short s16[16]; uint4 v[2]; } pk;
#pragma unroll
        for (int u = 0; u < 16; ++u)
            pk.s16[u] = tile[(seg * 16 + u) * TP_PAD + nl];
        uint4* dst = (uint4*)(Wt + (size_t)np * KCAT + k0 + seg * 16);
        dst[0] = pk.v[0];
        dst[1] = pk.v[1];
    }
}

// ---------------- fused GEMM + LSTM epilogue ----------------
#define BM 128
#define BN 128
#define BK 32

__global__ __launch_bounds__(256)
void lstm_fused(const unsigned short* __restrict__ Xcat,
                const unsigned short* __restrict__ Wt,
                const float* __restrict__ c_prev,
                const float* __restrict__ bix, const float* __restrict__ bih,
                const float* __restrict__ bbx, const float* __restrict__ bbh,
                float* __restrict__ out_h, float* __restrict__ out_c) {
    __shared__ unsigned short As[BM * BK];   // 8 KB
    __shared__ unsigned short Bs[BN * BK];   // 8 KB
    const int t    = threadIdx.x;
    const int lane = t & 63;
    const int wave = t >> 6;
    const int wm   = (wave >> 1) * 64;
    const int wn   = (wave & 1) * 64;
    const int m0   = blockIdx.y * BM;
    const int n0   = blockIdx.x * BN;

    floatx4 acc[4][4];
#pragma unroll
    for (int i = 0; i < 4; ++i)
#pragma unroll
        for (int g = 0; g < 4; ++g) acc[i][g] = (floatx4){0.f, 0.f, 0.f, 0.f};

    // Staging: LDS slot (row r = t>>2, cs = t&3) holds global chunk cs ^ s(r),
    // s(r) = (r + (r>>2)) & 3  (s(64+r) == s(r), so both halves share cg).
    const int lrow = t >> 2;
    const int cg   = ((t & 3) ^ (lrow + (lrow >> 2))) & 3;
    const int lcol = cg * 8;

    // Fragment read: chunk c lives in slot c ^ s(r); for r = (mult of 16)+lm,
    // s(r) = (lm + (lm>>2)) & 3 -> lane-constant slot index.
    const int lm  = lane & 15;
    const int fcs = ((lane >> 4) ^ (lm + (lm >> 2))) & 3;

    for (int kk = 0; kk < KCAT; kk += BK) {
        __syncthreads();   // previous tile fully consumed
        gl2lds16(Xcat + (size_t)(m0 + lrow)      * KCAT + kk + lcol, &As[t * 8]);
        gl2lds16(Xcat + (size_t)(m0 + lrow + 64) * KCAT + kk + lcol, &As[t * 8 + 2048]);
        gl2lds16(Wt   + (size_t)(n0 + lrow)      * KCAT + kk + lcol, &Bs[t * 8]);
        gl2lds16(Wt   + (size_t)(n0 + lrow + 64) * KCAT + kk + lcol, &Bs[t * 8 + 2048]);
        __syncthreads();   // drains vmcnt(0) for global_load_lds

        bf16x8 a[4], b[4];
#pragma unroll
        for (int i = 0; i < 4; ++i)
            a[i] = *(const bf16x8*)&As[(wm + i * 16 + lm) * BK + fcs * 8];
#pragma unroll
        for (int g = 0; g < 4; ++g)
            b[g] = *(const bf16x8*)&Bs[(wn + g * 16 + lm) * BK + fcs * 8];
#pragma unroll
        for (int i = 0; i < 4; ++i)
#pragma unroll
            for (int g = 0; g < 4; ++g)
                acc[i][g] = __builtin_amdgcn_mfma_f32_16x16x32_bf16(a[i], b[g], acc[i][g], 0, 0, 0);
    }

    // Epilogue: acc[i][g][r] = preact of gate g (i,f,o,a) at
    // m = m0+wm+i*16+(lane>>4)*4+r, j = ((n0+wn)>>6)*16 + lm.
    const int j  = (((n0 + wn) >> 6) << 4) + lm;
    const float bi = bix[j]           + bih[j];
    const float bf = bix[HID + j]     + bih[HID + j];
    const float bo = bix[2 * HID + j] + bih[2 * HID + j];
    const float ba = bbx[j]           + bbh[j];
#pragma unroll
    for (int i = 0; i < 4; ++i) {
#pragma unroll
        for (int r = 0; r < 4; ++r) {
            int m = m0 + wm + i * 16 + ((lane >> 4) * 4) + r;
            float pi = acc[i][0][r] + bi;
            float pf = acc[i][1][r] + bf;
            float po = acc[i][2][r] + bo;
            float pa = acc[i][3][r] + ba;
            float ig = 1.f / (1.f + __expf(-pi));
            float fg = 1.f / (1.f + __expf(-pf));
            float og = 1.f / (1.f + __expf(-po));
            float av = 2.f / (1.f + __expf(-2.f * pa)) - 1.f;
            float cp = c_prev[(size_t)m * HID + j];
            float cv = ig * av + fg * cp;
            float hv = og * (2.f / (1.f + __expf(-2.f * cv)) - 1.f);
            out_h[(size_t)m * HID + j] = hv;
            out_c[(size_t)m * HID + j] = cv;
        }
    }
}

// ---------------- naive fallback (ws too small) ----------------
__global__ void naive_lstm(const float* __restrict__ x, const float* __restrict__ h,
                           const float* __restrict__ cvp,
                           const float* __restrict__ Wix, const float* __restrict__ bix,
                           const float* __restrict__ Wih, const float* __restrict__ bih,
                           const float* __restrict__ Wbx, const float* __restrict__ bbx,
                           const float* __restrict__ Wbh, const float* __restrict__ bbh,
                           float* __restrict__ out_h, float* __restrict__ out_c) {
    const int j = blockIdx.x * 256 + threadIdx.x;
    const int m = blockIdx.y;
    float ai = 0.f, af = 0.f, ao = 0.f, aa = 0.f;
    for (int k = 0; k < FEAT; ++k) {
        float xk = x[(size_t)m * FEAT + k];
        ai += xk * Wix[(size_t)k * 3072 + j];
        af += xk * Wix[(size_t)k * 3072 + HID + j];
        ao += xk * Wix[(size_t)k * 3072 + 2 * HID + j];
        aa += xk * Wbx[(size_t)k * HID + j];
    }
    for (int k = 0; k < HID; ++k) {
        float hk = h[(size_t)m * HID + k];
        ai += hk * Wih[(size_t)k * 3072 + j];
        af += hk * Wih[(size_t)k * 3072 + HID + j];
        ao += hk * Wih[(size_t)k * 3072 + 2 * HID + j];
        aa += hk * Wbh[(size_t)k * HID + j];
    }
    ai += bix[j] + bih[j];
    af += bix[HID + j] + bih[HID + j];
    ao += bix[2 * HID + j] + bih[2 * HID + j];
    aa += bbx[j] + bbh[j];
    float ig = 1.f / (1.f + __expf(-ai));
    float fg = 1.f / (1.f + __expf(-af));
    float og = 1.f / (1.f + __expf(-ao));
    float av = 2.f / (1.f + __expf(-2.f * aa)) - 1.f;
    float cp = cvp[(size_t)m * HID + j];
    float cc = ig * av + fg * cp;
    float hh = og * (2.f / (1.f + __expf(-2.f * cc)) - 1.f);
    out_h[(size_t)m * HID + j] = hh;
    out_c[(size_t)m * HID + j] = cc;
}

extern "C" void kernel_launch(void* const* d_in, const int* in_sizes, int n_in,
                              void* d_out, int out_size, void* d_ws, size_t ws_size,
                              hipStream_t stream) {
    const float* x   = (const float*)d_in[0];
    const float* h   = (const float*)d_in[1];
    const float* c   = (const float*)d_in[2];
    const float* Wix = (const float*)d_in[3];
    const float* bix = (const float*)d_in[4];
    const float* Wih = (const float*)d_in[5];
    const float* bih = (const float*)d_in[6];
    const float* Wbx = (const float*)d_in[7];
    const float* bbx = (const float*)d_in[8];
    const float* Wbh = (const float*)d_in[9];
    const float* bbh = (const float*)d_in[10];

    float* out_h = (float*)d_out;
    float* out_c = out_h + (size_t)BATCH * HID;

    const size_t WT_BYTES = (size_t)NCAT * KCAT * 2;    // 16 MiB
    const size_t XC_BYTES = (size_t)BATCH * KCAT * 2;   // 16 MiB
    if (ws_size >= WT_BYTES + XC_BYTES) {
        unsigned short* Wt   = (unsigned short*)d_ws;
        unsigned short* Xcat = (unsigned short*)((char*)d_ws + WT_BYTES);
        pack_all<<<BATCH + 2048, 256, 0, stream>>>(x, h, Wix, Wih, Wbx, Wbh, Xcat, Wt);
        lstm_fused<<<dim3(NCAT / BN, BATCH / BM), 256, 0, stream>>>(
            Xcat, Wt, c, bix, bih, bbx, bbh, out_h, out_c);
    } else {
        naive_lstm<<<dim3(HID / 256, BATCH), 256, 0, stream>>>(
            x, h, c, Wix, bix, Wih, bih, Wbx, bbx, Wbh, bbh, out_h, out_c);
    }
}